// Round 4
// baseline (555.991 us; speedup 1.0000x reference)
//
#include <hip/hip_runtime.h>
#include <cfloat>

#define N_NODES 8192
#define F_IN    128
#define F_OUT   64
#define HEADS   2
#define LEAKY   0.2f
#define CAP     128   // per-row neighbor cap; Binomial(8192,0.004) max ~62 incl. self-loop
#define FROWS   16    // rows of X per feats block
#define MPR     (N_NODES / 64)   // 128 u64 masks per row
#define NCW     8192  // compress waves (grid-stride over 256K 1KB chunks)
#define REPS    5     // DIAGNOSTIC: repeat the A-stream 5x so stage1 exceeds the
                      // 159us fill wall and its counter row becomes visible.

typedef float f32x4 __attribute__((ext_vector_type(4)));

// ---------------------------------------------------------------------------
// Stage 1a: A -> bitmap, grid-stride sweep (R3 structure, unchanged except the
// REPS diagnostic loop). Chunk c covers A[row][pos*256..+256), row=c>>5,
// pos=c&31; 4 ballots land at bmp[c*4..+4).
//   bit l of mask (c*4+comp)  <->  A[row][pos*256 + 4*l + comp]
// ---------------------------------------------------------------------------
__device__ __forceinline__ void compress_chunks(
    const float* __restrict__ A, unsigned long long* __restrict__ bmp, int cw)
{
    const int lane = threadIdx.x & 63;

    #pragma unroll 1
    for (int rep = 0; rep < REPS; ++rep) {
        // opaque zero offset: keeps SGPR-based addressing but defeats
        // cross-rep load CSE/hoisting
        size_t off = 0;
        asm volatile("" : "+s"(off));
        const f32x4* A4 = (const f32x4*)A + off;

        f32x4 v[8];
        #pragma unroll
        for (int t = 0; t < 8; ++t)
            v[t] = __builtin_nontemporal_load(
                &A4[((size_t)t * NCW + cw) * 64 + lane]);

        #pragma unroll
        for (int t = 0; t < 32; ++t) {
            const f32x4 x = v[t & 7];
            if (t < 24)
                v[t & 7] = __builtin_nontemporal_load(
                    &A4[((size_t)(t + 8) * NCW + cw) * 64 + lane]);
            const unsigned long long m0 = __ballot(x[0] > 0.5f);
            const unsigned long long m1 = __ballot(x[1] > 0.5f);
            const unsigned long long m2 = __ballot(x[2] > 0.5f);
            const unsigned long long m3 = __ballot(x[3] > 0.5f);
            ulonglong2 st;             // ballots are wave-uniform: all lanes hold them
            st.x = (lane == 0) ? m0 : m2;
            st.y = (lane == 0) ? m1 : m3;
            if (lane < 2)
                ((ulonglong2*)(bmp + ((size_t)t * NCW + cw) * 4))[lane] = st;
        }
    }
}

// ---------------------------------------------------------------------------
// Stage 1b: feats GEMM + attention-logit epilogue (every-5th block of the
// same dispatch). feats stored as float2{head0,head1} per (node,o).
// ---------------------------------------------------------------------------
__device__ __forceinline__ void feats_rows(
    const float* __restrict__ X, const float* __restrict__ W,
    const float* __restrict__ attn_self, const float* __restrict__ attn_neigh,
    float* __restrict__ feats, float* __restrict__ a_s, float* __restrict__ a_n,
    float* Xs, int fb)
{
    const int n0 = fb * FROWS;
    {
        f32x4* dst = (f32x4*)Xs;
        const f32x4* src = (const f32x4*)(X + (size_t)n0 * F_IN);
        for (int k = threadIdx.x; k < FROWS * F_IN / 4; k += 256)
            dst[k] = src[k];
    }
    __syncthreads();

    const int wave = threadIdx.x >> 6;
    const int lane = threadIdx.x & 63;
    const int h    = wave & 1;
    const int r0   = (wave >> 1) * 8;
    const float* Wh = W + (size_t)h * F_IN * F_OUT;

    float acc[8];
    #pragma unroll
    for (int r = 0; r < 8; ++r) acc[r] = 0.f;

    for (int f = 0; f < F_IN; ++f) {
        const float wv = Wh[f * F_OUT + lane];      // coalesced, L1-resident
        #pragma unroll
        for (int r = 0; r < 8; ++r)
            acc[r] += Xs[(r0 + r) * F_IN + f] * wv; // LDS broadcast reads
    }

    const float asv = attn_self[h * F_OUT + lane];
    const float anv = attn_neigh[h * F_OUT + lane];
    #pragma unroll
    for (int r = 0; r < 8; ++r) {
        const int n = n0 + r0 + r;
        const float v = acc[r];
        feats[((size_t)n * F_OUT + lane) * 2 + h] = v;   // float2 {h0,h1} per (n,o)
        float s = v * asv;
        float t = v * anv;
        #pragma unroll
        for (int off = 32; off > 0; off >>= 1) {
            s += __shfl_down(s, off);
            t += __shfl_down(t, off);
        }
        if (lane == 0) {
            a_s[n * 2 + h] = s;
            a_n[n * 2 + h] = t;
        }
    }
}

__global__ __launch_bounds__(256) void stage1_kernel(
    const float* __restrict__ X, const float* __restrict__ A,
    const float* __restrict__ W,
    const float* __restrict__ attn_self, const float* __restrict__ attn_neigh,
    float* __restrict__ feats, float* __restrict__ a_s, float* __restrict__ a_n,
    unsigned long long* __restrict__ bmp)
{
    __shared__ float Xs[FROWS * F_IN];   // 8 KB (feats blocks only)
    const int bid = blockIdx.x;          // 2560 blocks: 2048 compress + 512 feats
    if ((bid % 5) == 4) {                // block-uniform branch
        feats_rows(X, W, attn_self, attn_neigh, feats, a_s, a_n, Xs, bid / 5);
    } else {
        const int cb = (bid / 5) * 4 + (bid % 5);          // [0, 2048)
        compress_chunks(A, bmp, cb * 4 + (threadIdx.x >> 6));  // cw in [0, 8192)
    }
}

// ---------------------------------------------------------------------------
// Stage 2: one wave per row (unchanged from R3).
// ---------------------------------------------------------------------------
__global__ __launch_bounds__(256) void fused_row_kernel(
    const unsigned long long* __restrict__ bmp, const float* __restrict__ feats,
    const float* __restrict__ a_s, const float* __restrict__ a_n,
    const float* __restrict__ biases, float* __restrict__ out)
{
    __shared__ int   jj_s[4][CAP];   // 2 KB
    __shared__ float w0_s[4][CAP];   // 2 KB
    __shared__ float w1_s[4][CAP];   // 2 KB

    const int wave = threadIdx.x >> 6;
    const int lane = threadIdx.x & 63;
    const int row  = blockIdx.x * 4 + wave;

    int*   jj = jj_s[wave];
    float* w0 = w0_s[wave];
    float* w1 = w1_s[wave];

    // ---- Phase 1: bitmap -> compacted neighbor indices ----
    const ulonglong2 mm =
        ((const ulonglong2*)(bmp + (size_t)row * MPR))[lane];   // masks 2*lane, 2*lane+1
    const int cnt = __popcll(mm.x) + __popcll(mm.y);
    int x = cnt;
    #pragma unroll
    for (int off = 1; off < 64; off <<= 1) {        // inclusive prefix scan
        const int y = __shfl_up(x, off);
        if (lane >= off) x += y;
    }
    const int total = __shfl(x, 63);
    int p = x - cnt;                                // exclusive prefix
    // mask i=2*lane: pos=lane>>1, comp=(lane&1)*2 ; mask i+1: same pos, comp+1
    const int jbase = (lane >> 1) * 256 + (lane & 1) * 2;
    unsigned long long m = mm.x;
    while (m) {
        const int b = __builtin_ctzll(m); m &= m - 1;
        if (p < CAP) jj[p] = jbase + 4 * b;
        ++p;
    }
    m = mm.y;
    while (m) {
        const int b = __builtin_ctzll(m); m &= m - 1;
        if (p < CAP) jj[p] = jbase + 4 * b + 1;
        ++p;
    }
    const int count = min(total, CAP);              // self-loop -> count >= 1

    // ---- Phase 2: logits + softmax (both heads), shfl reductions ----
    const float2 as = ((const float2*)a_s)[row];
    float m0 = -FLT_MAX, m1 = -FLT_MAX;
    for (int k = lane; k < count; k += 64) {
        const float2 an = ((const float2*)a_n)[jj[k]];   // one 8B load per j
        float e0 = as.x + an.x;  e0 = e0 > 0.f ? e0 : LEAKY * e0;
        float e1 = as.y + an.y;  e1 = e1 > 0.f ? e1 : LEAKY * e1;
        w0[k] = e0; w1[k] = e1;
        m0 = fmaxf(m0, e0); m1 = fmaxf(m1, e1);
    }
    #pragma unroll
    for (int off = 32; off > 0; off >>= 1) {
        m0 = fmaxf(m0, __shfl_xor(m0, off));
        m1 = fmaxf(m1, __shfl_xor(m1, off));
    }
    float s0 = 0.f, s1 = 0.f;
    for (int k = lane; k < count; k += 64) {
        const float p0 = __expf(w0[k] - m0); w0[k] = p0; s0 += p0;
        const float p1 = __expf(w1[k] - m1); w1[k] = p1; s1 += p1;
    }
    #pragma unroll
    for (int off = 32; off > 0; off >>= 1) {
        s0 += __shfl_xor(s0, off);
        s1 += __shfl_xor(s1, off);
    }

    // ---- Phase 3: gather from float2-interleaved feats, 4-deep batches ----
    const float2* f2 = (const float2*)feats;
    float acc0 = 0.f, acc1 = 0.f;
    int k = 0;
    for (; k + 3 < count; k += 4) {
        const int j0 = jj[k], j1 = jj[k + 1], j2 = jj[k + 2], j3 = jj[k + 3];
        const float2 fa = f2[(size_t)j0 * F_OUT + lane];
        const float2 fb = f2[(size_t)j1 * F_OUT + lane];
        const float2 fc = f2[(size_t)j2 * F_OUT + lane];
        const float2 fd = f2[(size_t)j3 * F_OUT + lane];
        acc0 += w0[k]     * fa.x;  acc1 += w1[k]     * fa.y;
        acc0 += w0[k + 1] * fb.x;  acc1 += w1[k + 1] * fb.y;
        acc0 += w0[k + 2] * fc.x;  acc1 += w1[k + 2] * fc.y;
        acc0 += w0[k + 3] * fd.x;  acc1 += w1[k + 3] * fd.y;
    }
    for (; k < count; ++k) {
        const float2 fa = f2[(size_t)jj[k] * F_OUT + lane];
        acc0 += w0[k] * fa.x;
        acc1 += w1[k] * fa.y;
    }
    const float v = 0.5f * ((acc0 / s0 + biases[lane]) +
                            (acc1 / s1 + biases[F_OUT + lane]));
    out[(size_t)row * F_OUT + lane] = v > 0.f ? v : 0.f;   // mean + relu
}

extern "C" void kernel_launch(void* const* d_in, const int* in_sizes, int n_in,
                              void* d_out, int out_size, void* d_ws, size_t ws_size,
                              hipStream_t stream) {
    const float* X          = (const float*)d_in[0];  // [8192, 128]
    const float* A          = (const float*)d_in[1];  // [8192, 8192]
    const float* W          = (const float*)d_in[2];  // [2, 128, 64]
    const float* biases     = (const float*)d_in[3];  // [2, 64]
    const float* attn_self  = (const float*)d_in[4];  // [2, 64]
    const float* attn_neigh = (const float*)d_in[5];  // [2, 64]
    float* out = (float*)d_out;                       // [8192, 64]

    float* feats = (float*)d_ws;                              // [8192][64] float2 = 4 MB
    float* a_s   = feats + (size_t)HEADS * N_NODES * F_OUT;   // float2[8192]
    float* a_n   = a_s + HEADS * N_NODES;                     // float2[8192]
    unsigned long long* bmp =
        (unsigned long long*)(a_n + HEADS * N_NODES);         // 8192*128 u64 = 8 MB

    stage1_kernel<<<2560, 256, 0, stream>>>(
        X, A, W, attn_self, attn_neigh, feats, a_s, a_n, bmp);
    fused_row_kernel<<<N_NODES / 4, 256, 0, stream>>>(
        bmp, feats, a_s, a_n, biases, out);
}

// Round 5
// 448.203 us; speedup vs baseline: 1.2405x; 1.2405x over previous
//
#include <hip/hip_runtime.h>
#include <cfloat>

#define N_NODES 8192
#define F_IN    128
#define F_OUT   64
#define HEADS   2
#define LEAKY   0.2f
#define CAP     128   // per-row neighbor cap; Binomial(8192,0.004) max ~62 incl. self-loop
#define FROWS   16    // rows of X per feats block
#define MPR     (N_NODES / 64)   // 128 u64 masks per row
#define NCW     8192  // compress waves (grid-stride over 256K 1KB chunks)
#define REPS_F  8     // DIAGNOSTIC: repeat fused's work 8x so its dispatch exceeds
                      // the ~160us fill wall and its counter row becomes visible.

typedef float f32x4 __attribute__((ext_vector_type(4)));

// ---------------------------------------------------------------------------
// Stage 1a: A -> bitmap, grid-stride sweep (R3 structure, REPS diagnostic
// removed -- R4 measured marginal stream cost ~46us/rep, 31% HBM peak).
// Chunk c covers A[row][pos*256..+256), row=c>>5, pos=c&31; 4 ballots land at
// bmp[c*4..+4).   bit l of mask (c*4+comp) <-> A[row][pos*256 + 4*l + comp]
// ---------------------------------------------------------------------------
__device__ __forceinline__ void compress_chunks(
    const float* __restrict__ A, unsigned long long* __restrict__ bmp, int cw)
{
    const int lane = threadIdx.x & 63;
    const f32x4* A4 = (const f32x4*)A;

    f32x4 v[8];
    #pragma unroll
    for (int t = 0; t < 8; ++t)
        v[t] = __builtin_nontemporal_load(
            &A4[((size_t)t * NCW + cw) * 64 + lane]);

    #pragma unroll
    for (int t = 0; t < 32; ++t) {
        const f32x4 x = v[t & 7];
        if (t < 24)
            v[t & 7] = __builtin_nontemporal_load(
                &A4[((size_t)(t + 8) * NCW + cw) * 64 + lane]);
        const unsigned long long m0 = __ballot(x[0] > 0.5f);
        const unsigned long long m1 = __ballot(x[1] > 0.5f);
        const unsigned long long m2 = __ballot(x[2] > 0.5f);
        const unsigned long long m3 = __ballot(x[3] > 0.5f);
        ulonglong2 st;                 // ballots are wave-uniform: all lanes hold them
        st.x = (lane == 0) ? m0 : m2;
        st.y = (lane == 0) ? m1 : m3;
        if (lane < 2)
            ((ulonglong2*)(bmp + ((size_t)t * NCW + cw) * 4))[lane] = st;
    }
}

// ---------------------------------------------------------------------------
// Stage 1b: feats GEMM + attention-logit epilogue (every-5th block).
// feats stored as float2{head0,head1} per (node,o). a_s/a_n float2-interleaved.
// ---------------------------------------------------------------------------
__device__ __forceinline__ void feats_rows(
    const float* __restrict__ X, const float* __restrict__ W,
    const float* __restrict__ attn_self, const float* __restrict__ attn_neigh,
    float* __restrict__ feats, float* __restrict__ a_s, float* __restrict__ a_n,
    float* Xs, int fb)
{
    const int n0 = fb * FROWS;
    {
        f32x4* dst = (f32x4*)Xs;
        const f32x4* src = (const f32x4*)(X + (size_t)n0 * F_IN);
        for (int k = threadIdx.x; k < FROWS * F_IN / 4; k += 256)
            dst[k] = src[k];
    }
    __syncthreads();

    const int wave = threadIdx.x >> 6;
    const int lane = threadIdx.x & 63;
    const int h    = wave & 1;
    const int r0   = (wave >> 1) * 8;
    const float* Wh = W + (size_t)h * F_IN * F_OUT;

    float acc[8];
    #pragma unroll
    for (int r = 0; r < 8; ++r) acc[r] = 0.f;

    for (int f = 0; f < F_IN; ++f) {
        const float wv = Wh[f * F_OUT + lane];      // coalesced, L1-resident
        #pragma unroll
        for (int r = 0; r < 8; ++r)
            acc[r] += Xs[(r0 + r) * F_IN + f] * wv; // LDS broadcast reads
    }

    const float asv = attn_self[h * F_OUT + lane];
    const float anv = attn_neigh[h * F_OUT + lane];
    #pragma unroll
    for (int r = 0; r < 8; ++r) {
        const int n = n0 + r0 + r;
        const float v = acc[r];
        feats[((size_t)n * F_OUT + lane) * 2 + h] = v;   // float2 {h0,h1} per (n,o)
        float s = v * asv;
        float t = v * anv;
        #pragma unroll
        for (int off = 32; off > 0; off >>= 1) {
            s += __shfl_down(s, off);
            t += __shfl_down(t, off);
        }
        if (lane == 0) {
            a_s[n * 2 + h] = s;
            a_n[n * 2 + h] = t;
        }
    }
}

__global__ __launch_bounds__(256) void stage1_kernel(
    const float* __restrict__ X, const float* __restrict__ A,
    const float* __restrict__ W,
    const float* __restrict__ attn_self, const float* __restrict__ attn_neigh,
    float* __restrict__ feats, float* __restrict__ a_s, float* __restrict__ a_n,
    unsigned long long* __restrict__ bmp)
{
    __shared__ float Xs[FROWS * F_IN];   // 8 KB (feats blocks only)
    const int bid = blockIdx.x;          // 2560 blocks: 2048 compress + 512 feats
    if ((bid % 5) == 4) {                // block-uniform branch
        feats_rows(X, W, attn_self, attn_neigh, feats, a_s, a_n, Xs, bid / 5);
    } else {
        const int cb = (bid / 5) * 4 + (bid % 5);          // [0, 2048)
        compress_chunks(A, bmp, cb * 4 + (threadIdx.x >> 6));  // cw in [0, 8192)
    }
}

// ---------------------------------------------------------------------------
// Stage 2: one wave per row. DIAGNOSTIC: whole body repeated REPS_F times
// (idempotent -- identical values rewritten; opaque SGPR offset defeats
// cross-rep CSE). Everything else identical to R3.
// ---------------------------------------------------------------------------
__global__ __launch_bounds__(256) void fused_row_kernel(
    const unsigned long long* __restrict__ bmp, const float* __restrict__ feats,
    const float* __restrict__ a_s, const float* __restrict__ a_n,
    const float* __restrict__ biases, float* __restrict__ out)
{
    __shared__ int   jj_s[4][CAP];   // 2 KB
    __shared__ float w0_s[4][CAP];   // 2 KB
    __shared__ float w1_s[4][CAP];   // 2 KB

    const int wave = threadIdx.x >> 6;
    const int lane = threadIdx.x & 63;
    const int row  = blockIdx.x * 4 + wave;

    int*   jj = jj_s[wave];
    float* w0 = w0_s[wave];
    float* w1 = w1_s[wave];

    #pragma unroll 1
    for (int rep = 0; rep < REPS_F; ++rep) {
        // opaque zero offset: keeps SGPR addressing, defeats cross-rep CSE
        size_t z = 0;
        asm volatile("" : "+s"(z));
        const unsigned long long* bmp_r   = bmp + z;
        const float*              feats_r = feats + z;
        const float*              a_n_r   = a_n + z;

        // ---- Phase 1: bitmap -> compacted neighbor indices ----
        const ulonglong2 mm =
            ((const ulonglong2*)(bmp_r + (size_t)row * MPR))[lane];
        const int cnt = __popcll(mm.x) + __popcll(mm.y);
        int x = cnt;
        #pragma unroll
        for (int off = 1; off < 64; off <<= 1) {    // inclusive prefix scan
            const int y = __shfl_up(x, off);
            if (lane >= off) x += y;
        }
        const int total = __shfl(x, 63);
        int p = x - cnt;                            // exclusive prefix
        // mask 2*lane: pos=lane>>1, comp=(lane&1)*2 ; mask 2*lane+1: comp+1
        const int jbase = (lane >> 1) * 256 + (lane & 1) * 2;
        unsigned long long m = mm.x;
        while (m) {
            const int b = __builtin_ctzll(m); m &= m - 1;
            if (p < CAP) jj[p] = jbase + 4 * b;
            ++p;
        }
        m = mm.y;
        while (m) {
            const int b = __builtin_ctzll(m); m &= m - 1;
            if (p < CAP) jj[p] = jbase + 4 * b + 1;
            ++p;
        }
        const int count = min(total, CAP);          // self-loop -> count >= 1

        // ---- Phase 2: logits + softmax (both heads), shfl reductions ----
        const float2 as = ((const float2*)a_s)[row];
        float m0 = -FLT_MAX, m1 = -FLT_MAX;
        for (int k = lane; k < count; k += 64) {
            const float2 an = ((const float2*)a_n_r)[jj[k]];
            float e0 = as.x + an.x;  e0 = e0 > 0.f ? e0 : LEAKY * e0;
            float e1 = as.y + an.y;  e1 = e1 > 0.f ? e1 : LEAKY * e1;
            w0[k] = e0; w1[k] = e1;
            m0 = fmaxf(m0, e0); m1 = fmaxf(m1, e1);
        }
        #pragma unroll
        for (int off = 32; off > 0; off >>= 1) {
            m0 = fmaxf(m0, __shfl_xor(m0, off));
            m1 = fmaxf(m1, __shfl_xor(m1, off));
        }
        float s0 = 0.f, s1 = 0.f;
        for (int k = lane; k < count; k += 64) {
            const float p0 = __expf(w0[k] - m0); w0[k] = p0; s0 += p0;
            const float p1 = __expf(w1[k] - m1); w1[k] = p1; s1 += p1;
        }
        #pragma unroll
        for (int off = 32; off > 0; off >>= 1) {
            s0 += __shfl_xor(s0, off);
            s1 += __shfl_xor(s1, off);
        }

        // ---- Phase 3: gather from float2-interleaved feats, 4-deep ----
        const float2* f2 = (const float2*)feats_r;
        float acc0 = 0.f, acc1 = 0.f;
        int k = 0;
        for (; k + 3 < count; k += 4) {
            const int j0 = jj[k], j1 = jj[k + 1], j2 = jj[k + 2], j3 = jj[k + 3];
            const float2 fa = f2[(size_t)j0 * F_OUT + lane];
            const float2 fb = f2[(size_t)j1 * F_OUT + lane];
            const float2 fc = f2[(size_t)j2 * F_OUT + lane];
            const float2 fd = f2[(size_t)j3 * F_OUT + lane];
            acc0 += w0[k]     * fa.x;  acc1 += w1[k]     * fa.y;
            acc0 += w0[k + 1] * fb.x;  acc1 += w1[k + 1] * fb.y;
            acc0 += w0[k + 2] * fc.x;  acc1 += w1[k + 2] * fc.y;
            acc0 += w0[k + 3] * fd.x;  acc1 += w1[k + 3] * fd.y;
        }
        for (; k < count; ++k) {
            const float2 fa = f2[(size_t)jj[k] * F_OUT + lane];
            acc0 += w0[k] * fa.x;
            acc1 += w1[k] * fa.y;
        }
        const float v = 0.5f * ((acc0 / s0 + biases[lane]) +
                                (acc1 / s1 + biases[F_OUT + lane]));
        out[(size_t)row * F_OUT + lane] = v > 0.f ? v : 0.f;   // mean + relu
    }
}

extern "C" void kernel_launch(void* const* d_in, const int* in_sizes, int n_in,
                              void* d_out, int out_size, void* d_ws, size_t ws_size,
                              hipStream_t stream) {
    const float* X          = (const float*)d_in[0];  // [8192, 128]
    const float* A          = (const float*)d_in[1];  // [8192, 8192]
    const float* W          = (const float*)d_in[2];  // [2, 128, 64]
    const float* biases     = (const float*)d_in[3];  // [2, 64]
    const float* attn_self  = (const float*)d_in[4];  // [2, 64]
    const float* attn_neigh = (const float*)d_in[5];  // [2, 64]
    float* out = (float*)d_out;                       // [8192, 64]

    float* feats = (float*)d_ws;                              // [8192][64] float2 = 4 MB
    float* a_s   = feats + (size_t)HEADS * N_NODES * F_OUT;   // float2[8192]
    float* a_n   = a_s + HEADS * N_NODES;                     // float2[8192]
    unsigned long long* bmp =
        (unsigned long long*)(a_n + HEADS * N_NODES);         // 8192*128 u64 = 8 MB

    stage1_kernel<<<2560, 256, 0, stream>>>(
        X, A, W, attn_self, attn_neigh, feats, a_s, a_n, bmp);
    fused_row_kernel<<<N_NODES / 4, 256, 0, stream>>>(
        bmp, feats, a_s, a_n, biases, out);
}

// Round 7
// 364.986 us; speedup vs baseline: 1.5233x; 1.2280x over previous
//
#include <hip/hip_runtime.h>
#include <cfloat>

#define N_NODES 8192
#define F_IN    128
#define F_OUT   64
#define HEADS   2
#define LEAKY   0.2f
#define CAP     128   // per-row neighbor cap; Binomial(8192,0.004) max ~62 incl. self-loop
#define FROWS   16    // rows of X per feats block
#define MPR     (N_NODES / 64)   // 128 u64 masks per row
#define NCW     4096  // compress waves: exact-residency sweep (R6)

typedef float f32x4 __attribute__((ext_vector_type(4)));

// ---------------------------------------------------------------------------
// Stage 1a: A -> bitmap, EXACT-RESIDENCY grid-stride sweep (R6 change).
// R3's sweep launched 10240 waves vs 8192-wave capacity: 20% of blocks start
// late and sweep out of phase. Now 4096 compress waves (+2048 feats waves =
// 6144 < 8192) are ALL co-resident: at iter t the whole machine reads one
// contiguous 4MB window [t*4MB, (t+1)*4MB), moving linearly start-to-end.
// Each wave: 64 chunks of 1KB, 8-deep NT pipeline (R2: cached regressed).
// Chunk c covers A[flat c*256..+256), row=c>>5, pos=c&31; 4 ballots -> bmp[c*4..+4)
// (chunk-major == row-major).  bit l of mask (c*4+comp) <-> A[row][pos*256+4*l+comp]
// ---------------------------------------------------------------------------
__device__ __forceinline__ void compress_chunks(
    const float* __restrict__ A, unsigned long long* __restrict__ bmp, int cw)
{
    const int lane = threadIdx.x & 63;
    const f32x4* A4 = (const f32x4*)A;

    f32x4 v[8];
    #pragma unroll
    for (int t = 0; t < 8; ++t)
        v[t] = __builtin_nontemporal_load(
            &A4[((size_t)t * NCW + cw) * 64 + lane]);

    #pragma unroll 8   // multiple of 8: keeps v[t&7] statically indexed (no scratch)
    for (int t = 0; t < 64; ++t) {
        const f32x4 x = v[t & 7];
        if (t < 56)
            v[t & 7] = __builtin_nontemporal_load(
                &A4[((size_t)(t + 8) * NCW + cw) * 64 + lane]);
        const unsigned long long m0 = __ballot(x[0] > 0.5f);
        const unsigned long long m1 = __ballot(x[1] > 0.5f);
        const unsigned long long m2 = __ballot(x[2] > 0.5f);
        const unsigned long long m3 = __ballot(x[3] > 0.5f);
        ulonglong2 st;                 // ballots are wave-uniform: all lanes hold them
        st.x = (lane == 0) ? m0 : m2;
        st.y = (lane == 0) ? m1 : m3;
        if (lane < 2)
            ((ulonglong2*)(bmp + ((size_t)t * NCW + cw) * 4))[lane] = st;
    }
}

// ---------------------------------------------------------------------------
// Stage 1b: feats GEMM + attention-logit epilogue (every-3rd block now).
// feats stored as float2{head0,head1} per (node,o). a_s/a_n float2-interleaved.
// ---------------------------------------------------------------------------
__device__ __forceinline__ void feats_rows(
    const float* __restrict__ X, const float* __restrict__ W,
    const float* __restrict__ attn_self, const float* __restrict__ attn_neigh,
    float* __restrict__ feats, float* __restrict__ a_s, float* __restrict__ a_n,
    float* Xs, int fb)
{
    const int n0 = fb * FROWS;
    {
        f32x4* dst = (f32x4*)Xs;
        const f32x4* src = (const f32x4*)(X + (size_t)n0 * F_IN);
        for (int k = threadIdx.x; k < FROWS * F_IN / 4; k += 256)
            dst[k] = src[k];
    }
    __syncthreads();

    const int wave = threadIdx.x >> 6;
    const int lane = threadIdx.x & 63;
    const int h    = wave & 1;
    const int r0   = (wave >> 1) * 8;
    const float* Wh = W + (size_t)h * F_IN * F_OUT;

    float acc[8];
    #pragma unroll
    for (int r = 0; r < 8; ++r) acc[r] = 0.f;

    for (int f = 0; f < F_IN; ++f) {
        const float wv = Wh[f * F_OUT + lane];      // coalesced, L1-resident
        #pragma unroll
        for (int r = 0; r < 8; ++r)
            acc[r] += Xs[(r0 + r) * F_IN + f] * wv; // LDS broadcast reads
    }

    const float asv = attn_self[h * F_OUT + lane];
    const float anv = attn_neigh[h * F_OUT + lane];
    #pragma unroll
    for (int r = 0; r < 8; ++r) {
        const int n = n0 + r0 + r;
        const float v = acc[r];
        feats[((size_t)n * F_OUT + lane) * 2 + h] = v;   // float2 {h0,h1} per (n,o)
        float s = v * asv;
        float t = v * anv;
        #pragma unroll
        for (int off = 32; off > 0; off >>= 1) {
            s += __shfl_down(s, off);
            t += __shfl_down(t, off);
        }
        if (lane == 0) {
            a_s[n * 2 + h] = s;
            a_n[n * 2 + h] = t;
        }
    }
}

__global__ __launch_bounds__(256) void stage1_kernel(
    const float* __restrict__ X, const float* __restrict__ A,
    const float* __restrict__ W,
    const float* __restrict__ attn_self, const float* __restrict__ attn_neigh,
    float* __restrict__ feats, float* __restrict__ a_s, float* __restrict__ a_n,
    unsigned long long* __restrict__ bmp)
{
    __shared__ float Xs[FROWS * F_IN];   // 8 KB (feats blocks only)
    const int bid = blockIdx.x;          // 1536 blocks = 6/CU exactly:
    if ((bid % 3) == 2) {                // 512 feats + 1024 compress, 2:1 interleave
        feats_rows(X, W, attn_self, attn_neigh, feats, a_s, a_n, Xs, bid / 3);
    } else {
        const int cb = (bid / 3) * 2 + (bid % 3);          // [0, 1024)
        compress_chunks(A, bmp, cb * 4 + (threadIdx.x >> 6));  // cw in [0, 4096)
    }
}

// ---------------------------------------------------------------------------
// Stage 2: one wave per row. Phase 1: bitmap -> compacted indices (popcount +
// shfl prefix scan + per-lane bit expansion; order within jj irrelevant).
// Phase 2 (R6): register-resident -- CAP=128 means each lane owns at most
// k=lane and k=lane+64, so logits live in regs; only the final softmax
// weights are written to LDS for phase 3's broadcast reads.
// ---------------------------------------------------------------------------
__global__ __launch_bounds__(256) void fused_row_kernel(
    const unsigned long long* __restrict__ bmp, const float* __restrict__ feats,
    const float* __restrict__ a_s, const float* __restrict__ a_n,
    const float* __restrict__ biases, float* __restrict__ out)
{
    __shared__ int   jj_s[4][CAP];   // 2 KB
    __shared__ float w0_s[4][CAP];   // 2 KB
    __shared__ float w1_s[4][CAP];   // 2 KB

    const int wave = threadIdx.x >> 6;
    const int lane = threadIdx.x & 63;
    const int row  = blockIdx.x * 4 + wave;

    int*   jj = jj_s[wave];
    float* w0 = w0_s[wave];
    float* w1 = w1_s[wave];

    // ---- Phase 1: bitmap -> compacted neighbor indices ----
    const ulonglong2 mm =
        ((const ulonglong2*)(bmp + (size_t)row * MPR))[lane];   // masks 2*lane, 2*lane+1
    const int cnt = __popcll(mm.x) + __popcll(mm.y);
    int x = cnt;
    #pragma unroll
    for (int off = 1; off < 64; off <<= 1) {        // inclusive prefix scan
        const int y = __shfl_up(x, off);
        if (lane >= off) x += y;
    }
    const int total = __shfl(x, 63);
    int p = x - cnt;                                // exclusive prefix
    // mask 2*lane: pos=lane>>1, comp=(lane&1)*2 ; mask 2*lane+1: comp+1
    const int jbase = (lane >> 1) * 256 + (lane & 1) * 2;
    unsigned long long m = mm.x;
    while (m) {
        const int b = __builtin_ctzll(m); m &= m - 1;
        if (p < CAP) jj[p] = jbase + 4 * b;
        ++p;
    }
    m = mm.y;
    while (m) {
        const int b = __builtin_ctzll(m); m &= m - 1;
        if (p < CAP) jj[p] = jbase + 4 * b + 1;
        ++p;
    }
    const int count = min(total, CAP);              // self-loop -> count >= 1

    // ---- Phase 2: logits + softmax, register-resident (2 k's per lane) ----
    const float2 as = ((const float2*)a_s)[row];
    const float2* an2 = (const float2*)a_n;
    const bool hasA = lane < count;
    const bool hasB = lane + 64 < count;
    float e0a = -FLT_MAX, e1a = -FLT_MAX, e0b = -FLT_MAX, e1b = -FLT_MAX;
    if (hasA) {
        const float2 an = an2[jj[lane]];
        e0a = as.x + an.x;  e0a = e0a > 0.f ? e0a : LEAKY * e0a;
        e1a = as.y + an.y;  e1a = e1a > 0.f ? e1a : LEAKY * e1a;
    }
    if (hasB) {
        const float2 an = an2[jj[lane + 64]];
        e0b = as.x + an.x;  e0b = e0b > 0.f ? e0b : LEAKY * e0b;
        e1b = as.y + an.y;  e1b = e1b > 0.f ? e1b : LEAKY * e1b;
    }
    float m0 = fmaxf(e0a, e0b), m1 = fmaxf(e1a, e1b);
    #pragma unroll
    for (int off = 32; off > 0; off >>= 1) {
        m0 = fmaxf(m0, __shfl_xor(m0, off));
        m1 = fmaxf(m1, __shfl_xor(m1, off));
    }
    const float p0a = hasA ? __expf(e0a - m0) : 0.f;
    const float p1a = hasA ? __expf(e1a - m1) : 0.f;
    const float p0b = hasB ? __expf(e0b - m0) : 0.f;
    const float p1b = hasB ? __expf(e1b - m1) : 0.f;
    if (hasA) { w0[lane] = p0a;      w1[lane] = p1a; }
    if (hasB) { w0[lane + 64] = p0b; w1[lane + 64] = p1b; }
    float s0 = p0a + p0b, s1 = p1a + p1b;
    #pragma unroll
    for (int off = 32; off > 0; off >>= 1) {
        s0 += __shfl_xor(s0, off);
        s1 += __shfl_xor(s1, off);
    }

    // ---- Phase 3: gather from float2-interleaved feats, 4-deep batches ----
    const float2* f2 = (const float2*)feats;
    float acc0 = 0.f, acc1 = 0.f;
    int k = 0;
    for (; k + 3 < count; k += 4) {
        const int j0 = jj[k], j1 = jj[k + 1], j2 = jj[k + 2], j3 = jj[k + 3];
        const float2 fa = f2[(size_t)j0 * F_OUT + lane];
        const float2 fb = f2[(size_t)j1 * F_OUT + lane];
        const float2 fc = f2[(size_t)j2 * F_OUT + lane];
        const float2 fd = f2[(size_t)j3 * F_OUT + lane];
        acc0 += w0[k]     * fa.x;  acc1 += w1[k]     * fa.y;
        acc0 += w0[k + 1] * fb.x;  acc1 += w1[k + 1] * fb.y;
        acc0 += w0[k + 2] * fc.x;  acc1 += w1[k + 2] * fc.y;
        acc0 += w0[k + 3] * fd.x;  acc1 += w1[k + 3] * fd.y;
    }
    for (; k < count; ++k) {
        const float2 fa = f2[(size_t)jj[k] * F_OUT + lane];
        acc0 += w0[k] * fa.x;
        acc1 += w1[k] * fa.y;
    }
    const float v = 0.5f * ((acc0 / s0 + biases[lane]) +
                            (acc1 / s1 + biases[F_OUT + lane]));
    out[(size_t)row * F_OUT + lane] = v > 0.f ? v : 0.f;   // mean + relu
}

extern "C" void kernel_launch(void* const* d_in, const int* in_sizes, int n_in,
                              void* d_out, int out_size, void* d_ws, size_t ws_size,
                              hipStream_t stream) {
    const float* X          = (const float*)d_in[0];  // [8192, 128]
    const float* A          = (const float*)d_in[1];  // [8192, 8192]
    const float* W          = (const float*)d_in[2];  // [2, 128, 64]
    const float* biases     = (const float*)d_in[3];  // [2, 64]
    const float* attn_self  = (const float*)d_in[4];  // [2, 64]
    const float* attn_neigh = (const float*)d_in[5];  // [2, 64]
    float* out = (float*)d_out;                       // [8192, 64]

    float* feats = (float*)d_ws;                              // [8192][64] float2 = 4 MB
    float* a_s   = feats + (size_t)HEADS * N_NODES * F_OUT;   // float2[8192]
    float* a_n   = a_s + HEADS * N_NODES;                     // float2[8192]
    unsigned long long* bmp =
        (unsigned long long*)(a_n + HEADS * N_NODES);         // 8192*128 u64 = 8 MB

    stage1_kernel<<<1536, 256, 0, stream>>>(
        X, A, W, attn_self, attn_neigh, feats, a_s, a_n, bmp);
    fused_row_kernel<<<N_NODES / 4, 256, 0, stream>>>(
        bmp, feats, a_s, a_n, biases, out);
}